// Round 6
// baseline (638.746 us; speedup 1.0000x reference)
//
#include <hip/hip_runtime.h>
#include <stdint.h>

// Problem constants (fixed by setup_inputs)
#define N_ROWS  32768
#define D_DIM   512
#define K_CODES 8192
#define BM 128
#define BN 128
#define BK 64
#define NTILES (K_CODES / BN)   // 64 code-tiles per row

typedef __attribute__((ext_vector_type(8))) short short8;
typedef __attribute__((ext_vector_type(4))) float f32x4;
typedef unsigned long long u64;
typedef unsigned int u32;
typedef unsigned short u16;

// ---------- helpers ----------

__device__ __forceinline__ u16 bf_rne(float f) {
    // round-to-nearest-even fp32 -> bf16 (inputs are finite)
    u32 u = __float_as_uint(f);
    u32 r = (u + 0x7FFFu + ((u >> 16) & 1u)) >> 16;
    return (u16)r;
}

__device__ __forceinline__ u32 fkey(float f) {
    // monotonic (order-preserving) float -> uint transform
    u32 u = __float_as_uint(f);
    return (u & 0x80000000u) ? ~u : (u | 0x80000000u);
}

__device__ __forceinline__ void top2_merge(u64 &a1, u64 &a2, u64 b1, u64 b2) {
    u64 lo = a1 < b1 ? a1 : b1;
    u64 hi = a1 < b1 ? b1 : a1;
    u64 c  = a2 < b2 ? a2 : b2;
    a1 = lo;
    a2 = hi < c ? hi : c;
}

__device__ __forceinline__ void cswap(u64 &a, u64 &b) {
    u64 lo = a < b ? a : b;
    u64 hi = a < b ? b : a;
    a = lo; b = hi;
}

__device__ __forceinline__ void gll16(const void* g, void* l) {
    // async global->LDS, 16B per lane; LDS dest = wave-uniform base + lane*16
    __builtin_amdgcn_global_load_lds((const __attribute__((address_space(1))) void*)g,
                                     (__attribute__((address_space(3))) void*)l,
                                     16, 0, 0);
}

// ---------- prep: fp32 -> bf16 (RNE) + optional row sum-of-squares ----------

__global__ __launch_bounds__(256) void prep_bf16(const float* __restrict__ src,
                                                 u16* __restrict__ hp,
                                                 float* __restrict__ np) {
    int row  = blockIdx.x * 4 + (threadIdx.x >> 6);
    int lane = threadIdx.x & 63;
    const float* s = src + (size_t)row * D_DIM + lane * 8;
    float4 a = *(const float4*)(s);
    float4 b = *(const float4*)(s + 4);
    float v[8] = {a.x, a.y, a.z, a.w, b.x, b.y, b.z, b.w};
    short8 hv;
    float sum = 0.f;
#pragma unroll
    for (int j = 0; j < 8; j++) {
        hv[j] = (short)bf_rne(v[j]);
        sum += v[j] * v[j];
    }
    *(short8*)(hp + (size_t)row * D_DIM + lane * 8) = hv;
    if (np != nullptr) {
#pragma unroll
        for (int mask = 1; mask < 64; mask <<= 1)
            sum += __shfl_xor(sum, mask, 64);
        if (lane == 0) np[row] = sum;
    }
}

// ---------- main: bf16 GEMM (approx -2*x.c) + per-row top-2 over this 128-code tile ----------
// dist_approx(i,j) = cnorm[j] - 2 * (xh . ch)   -- candidate SELECTION only; finalize
// re-ranks the global top-4 in exact fp32, so bf16 rounding error is tolerated.
// 2-phase pipeline (T3 minimum): double-buffered LDS, next K-step's global_load_lds
// issued BEFORE current compute; __syncthreads' vmcnt-drain lands loads that had a
// full MFMA phase in flight.

__global__ __launch_bounds__(256, 2) void qgemm(const u16* __restrict__ xh,
                                                const u16* __restrict__ ch,
                                                const float* __restrict__ cnorm,
                                                ulonglong2* __restrict__ tileres) {
    // LDS: 2 bufs x (A [128][64] bf16 16KB + B same) = 64KB -> 2 blocks/CU.
    __shared__ char smem[65536];

    // XCD mapping, tileN-FAST within an XCD: each XCD owns 8 tileN values whose
    // ch tiles (1MB) stay L2-resident for the whole sweep; each xh tile is read
    // once per XCD (8 consecutive blocks share it). L2-fill ~0.26GB vs 2GB for
    // tileM-fast. Bijective: (xcd 0..7) x (tileM 0..255) x (tn 0..7).
    int bid   = blockIdx.x;
    int xcd   = bid & 7;
    int local = bid >> 3;
    int tileM = local >> 3;              // 0..255
    int tileN = xcd * 8 + (local & 7);   // 0..63

    int tid  = threadIdx.x;
    int lane = tid & 63;
    int w    = tid >> 6;
    int wr   = w >> 1, wc = w & 1;   // wave -> 64x64 output quadrant

    f32x4 acc[4][4];
#pragma unroll
    for (int m = 0; m < 4; m++)
#pragma unroll
        for (int n = 0; n < 4; n++)
            acc[m][n] = (f32x4){0.f, 0.f, 0.f, 0.f};

    // Staging: 1024 16B-chunks per buffer; q = tid + 256*i; row=q>>3; chunk=q&7.
    // LDS written LINEARLY (global_load_lds constraint); XOR swizzle chunk^=(row&7)
    // applied on the GLOBAL source (rule #21: both-sides-or-neither). On the
    // ds_read side, bank-quad = chunk^(row&7): 16 consecutive rows cover all 8
    // quads twice -> 2 lanes/quad = free (m136).
    size_t aoff[4], boff[4];
    int ldsq[4];
#pragma unroll
    for (int i = 0; i < 4; i++) {
        int q   = tid + 256 * i;
        int row = q >> 3;
        int csw = (q & 7) ^ (row & 7);
        aoff[i] = ((size_t)(tileM * BM + row)) * D_DIM + csw * 8;
        boff[i] = ((size_t)(tileN * BN + row)) * D_DIM + csw * 8;
        ldsq[i] = (w * 64 + 256 * i) * 16;   // wave-uniform LDS byte base
    }

    // prologue: stage K-step 0 into buf0
#pragma unroll
    for (int i = 0; i < 4; i++) {
        gll16(xh + aoff[i], smem +     0 + ldsq[i]);
        gll16(ch + boff[i], smem + 16384 + ldsq[i]);
    }
    __syncthreads();

    int cur = 0;
    for (int kk = 0; kk < D_DIM; kk += BK) {
        int nxt = cur ^ 1;
        if (kk + BK < D_DIM) {
            // issue next K-step's staging FIRST -> overlaps with compute below
#pragma unroll
            for (int i = 0; i < 4; i++) {
                gll16(xh + aoff[i] + kk + BK, smem + nxt * 32768 +     0 + ldsq[i]);
                gll16(ch + boff[i] + kk + BK, smem + nxt * 32768 + 16384 + ldsq[i]);
            }
        }
        const char* base = smem + cur * 32768;

        int klo = (lane >> 4) * 16;   // byte offset of this lane-quad's 8 bf16 within a 32-k subtile
        short8 b[2][4];
#pragma unroll
        for (int t = 0; t < 2; t++)
#pragma unroll
            for (int n = 0; n < 4; n++) {
                int rb = wc * 64 + n * 16 + (lane & 15);
                int cbyte = t * 64 + klo;
                int ad = rb * 128 + (cbyte ^ ((rb & 7) << 4));
                b[t][n] = *(const short8*)(base + 16384 + ad);
            }
#pragma unroll
        for (int m = 0; m < 4; m++) {
            int ra = wr * 64 + m * 16 + (lane & 15);
#pragma unroll
            for (int t = 0; t < 2; t++) {
                int cbyte = t * 64 + klo;
                int ad = ra * 128 + (cbyte ^ ((ra & 7) << 4));
                short8 a = *(const short8*)(base + ad);
#pragma unroll
                for (int n = 0; n < 4; n++)
                    acc[m][n] = __builtin_amdgcn_mfma_f32_16x16x32_bf16(a, b[t][n], acc[m][n], 0, 0, 0);
            }
        }
        __syncthreads();   // drains prefetch vmcnt + all waves done reading buf[cur]
        cur = nxt;
    }

    // ---- epilogue: dist + per-row top-2 across the 128 codes of this tile ----
    int cq = lane >> 4, cc = lane & 15;
    float cn[4];
#pragma unroll
    for (int n = 0; n < 4; n++)
        cn[n] = cnorm[tileN * BN + wc * 64 + n * 16 + cc];

    u64* sc = (u64*)smem;   // scratch [128 rows][2 wc][2] = 4KB (staging is dead now)

#pragma unroll
    for (int m = 0; m < 4; m++) {
#pragma unroll
        for (int r = 0; r < 4; r++) {
            u64 k1 = ~0ull, k2 = ~0ull;
#pragma unroll
            for (int n = 0; n < 4; n++) {
                float d = cn[n] - 2.0f * acc[m][n][r];
                u64 key = ((u64)fkey(d) << 32) | (u32)(tileN * BN + wc * 64 + n * 16 + cc);
                if (key < k1) { k2 = k1; k1 = key; }
                else if (key < k2) { k2 = key; }
            }
            // reduce across the 16 lanes sharing this row (C/D: col=lane&15)
#pragma unroll
            for (int mask = 1; mask < 16; mask <<= 1) {
                u64 o1 = __shfl_xor((unsigned long long)k1, mask, 16);
                u64 o2 = __shfl_xor((unsigned long long)k2, mask, 16);
                top2_merge(k1, k2, o1, o2);
            }
            if (cc == 0) {
                int rl = wr * 64 + m * 16 + cq * 4 + r;   // C/D: row=(lane>>4)*4+reg
                sc[rl * 4 + wc * 2 + 0] = k1;
                sc[rl * 4 + wc * 2 + 1] = k2;
            }
        }
    }
    __syncthreads();
    if (tid < 128) {
        u64 a1 = sc[tid * 4 + 0], a2 = sc[tid * 4 + 1];
        u64 b1 = sc[tid * 4 + 2], b2 = sc[tid * 4 + 3];
        top2_merge(a1, a2, b1, b2);
        ulonglong2 outv;
        outv.x = a1;   // sorted: x <= y
        outv.y = a2;
        tileres[(size_t)(tileM * BM + tid) * NTILES + tileN] = outv;
    }
}

// ---------- finalize: global top-4 merge, exact fp32 re-rank of 4 candidates,
//            gather emb (STE form), ids (as float), loss = 1.25 * ||x - emb||^2 ----------

__global__ __launch_bounds__(256) void finalize(const float* __restrict__ x, const float* __restrict__ cb,
                                                const ulonglong2* __restrict__ tileres,
                                                float* __restrict__ emb, float* __restrict__ idsf,
                                                float* __restrict__ lossf) {
    int row  = blockIdx.x * 4 + (threadIdx.x >> 6);
    int lane = threadIdx.x & 63;

    ulonglong2 t = tileres[(size_t)row * NTILES + lane];   // 64 tiles == 64 lanes
    // sorted 4-list per lane (keys unique: id in low bits)
    u64 k0 = t.x, k1 = t.y, k2 = ~0ull, k3 = ~0ull;
    // butterfly merge: lowest-4 of two sorted 4-lists via bitonic half-cleaner
#pragma unroll
    for (int mask = 1; mask < 64; mask <<= 1) {
        u64 p0 = __shfl_xor((unsigned long long)k0, mask, 64);
        u64 p1 = __shfl_xor((unsigned long long)k1, mask, 64);
        u64 p2 = __shfl_xor((unsigned long long)k2, mask, 64);
        u64 p3 = __shfl_xor((unsigned long long)k3, mask, 64);
        u64 m0 = k0 < p3 ? k0 : p3;
        u64 m1 = k1 < p2 ? k1 : p2;
        u64 m2 = k2 < p1 ? k2 : p1;
        u64 m3 = k3 < p0 ? k3 : p0;
        cswap(m0, m2); cswap(m1, m3); cswap(m0, m1); cswap(m2, m3);
        k0 = m0; k1 = m1; k2 = m2; k3 = m3;
    }
    u32 id0 = (u32)(k0 & 0xFFFFFFFFull);
    u32 id1 = (u32)(k1 & 0xFFFFFFFFull);
    u32 id2 = (u32)(k2 & 0xFFFFFFFFull);
    u32 id3 = (u32)(k3 & 0xFFFFFFFFull);

    const float* xr = x + (size_t)row * D_DIM + lane * 8;
    float4 xa = *(const float4*)xr, xb = *(const float4*)(xr + 4);
    float xv[8] = {xa.x, xa.y, xa.z, xa.w, xb.x, xb.y, xb.z, xb.w};

    const float* c0p = cb + (size_t)id0 * D_DIM + lane * 8;
    const float* c1p = cb + (size_t)id1 * D_DIM + lane * 8;
    const float* c2p = cb + (size_t)id2 * D_DIM + lane * 8;
    const float* c3p = cb + (size_t)id3 * D_DIM + lane * 8;
    float4 a0 = *(const float4*)c0p, b0 = *(const float4*)(c0p + 4);
    float4 a1 = *(const float4*)c1p, b1 = *(const float4*)(c1p + 4);
    float4 a2 = *(const float4*)c2p, b2 = *(const float4*)(c2p + 4);
    float4 a3 = *(const float4*)c3p, b3 = *(const float4*)(c3p + 4);
    float v0[8] = {a0.x, a0.y, a0.z, a0.w, b0.x, b0.y, b0.z, b0.w};
    float v1[8] = {a1.x, a1.y, a1.z, a1.w, b1.x, b1.y, b1.z, b1.w};
    float v2[8] = {a2.x, a2.y, a2.z, a2.w, b2.x, b2.y, b2.z, b2.w};
    float v3[8] = {a3.x, a3.y, a3.z, a3.w, b3.x, b3.y, b3.z, b3.w};

    float s0 = 0.f, s1 = 0.f, s2 = 0.f, s3 = 0.f;
#pragma unroll
    for (int j = 0; j < 8; j++) {
        float d0 = xv[j] - v0[j]; s0 += d0 * d0;
        float d1 = xv[j] - v1[j]; s1 += d1 * d1;
        float d2 = xv[j] - v2[j]; s2 += d2 * d2;
        float d3 = xv[j] - v3[j]; s3 += d3 * d3;
    }
#pragma unroll
    for (int mask = 1; mask < 64; mask <<= 1) {
        s0 += __shfl_xor(s0, mask, 64);
        s1 += __shfl_xor(s1, mask, 64);
        s2 += __shfl_xor(s2, mask, 64);
        s3 += __shfl_xor(s3, mask, 64);
    }

    // exact argmin over the 4 candidates; tie -> smaller index (jnp.argmin first-occurrence)
    float bs = s0; u32 bi = id0; int bj = 0;
    bool t1 = (s1 < bs) || (s1 == bs && id1 < bi); bs = t1 ? s1 : bs; bi = t1 ? id1 : bi; bj = t1 ? 1 : bj;
    bool t2 = (s2 < bs) || (s2 == bs && id2 < bi); bs = t2 ? s2 : bs; bi = t2 ? id2 : bi; bj = t2 ? 2 : bj;
    bool t3 = (s3 < bs) || (s3 == bs && id3 < bi); bs = t3 ? s3 : bs; bi = t3 ? id3 : bi; bj = t3 ? 3 : bj;

    float ev[8];
#pragma unroll
    for (int j = 0; j < 8; j++) {
        float cj = (bj == 0) ? v0[j] : (bj == 1) ? v1[j] : (bj == 2) ? v2[j] : v3[j];
        ev[j] = xv[j] + (cj - xv[j]);   // replicate reference's x + (emb - x)
    }
    float* op = emb + (size_t)row * D_DIM + lane * 8;
    *(float4*)op       = (float4){ev[0], ev[1], ev[2], ev[3]};
    *(float4*)(op + 4) = (float4){ev[4], ev[5], ev[6], ev[7]};

    if (lane == 0) {
        idsf[row]  = (float)bi;
        lossf[row] = 1.25f * bs;   // emb_loss + 0.25*query_loss, both == ||x-emb||^2
    }
}

// ---------- launch ----------

extern "C" void kernel_launch(void* const* d_in, const int* in_sizes, int n_in,
                              void* d_out, int out_size, void* d_ws, size_t ws_size,
                              hipStream_t stream) {
    const float* x  = (const float*)d_in[0];
    const float* cb = (const float*)d_in[1];
    char* ws = (char*)d_ws;

    // workspace layout (bytes)
    u16*   xh    = (u16*)(ws + 0);                      // 32 MB
    u16*   ch    = (u16*)(ws + 33554432);               //  8 MB
    float* cnorm = (float*)(ws + 41943040);             // 32 KB
    ulonglong2* tileres = (ulonglong2*)(ws + 41975808); // 32 MB (total ~74 MB)

    float* emb   = (float*)d_out;
    float* idsf  = emb + (size_t)N_ROWS * D_DIM;
    float* lossf = idsf + N_ROWS;

    prep_bf16<<<dim3(K_CODES / 4), dim3(256), 0, stream>>>(cb, ch, cnorm);
    prep_bf16<<<dim3(N_ROWS / 4),  dim3(256), 0, stream>>>(x, xh, nullptr);
    qgemm<<<dim3((N_ROWS / BM) * (K_CODES / BN)), dim3(256), 0, stream>>>(xh, ch, cnorm, tileres);
    finalize<<<dim3(N_ROWS / 4), dim3(256), 0, stream>>>(x, cb, tileres, emb, idsf, lossf);
}

// Round 7
// 492.183 us; speedup vs baseline: 1.2978x; 1.2978x over previous
//
#include <hip/hip_runtime.h>
#include <stdint.h>

// Problem constants (fixed by setup_inputs)
#define N_ROWS  32768
#define D_DIM   512
#define K_CODES 8192
#define BM 128
#define BN 128
#define BK 64
#define NTILES (K_CODES / BN)   // 64 code-tiles total
#define TPB 8                   // code-tiles per block (one XCD's share)

typedef __attribute__((ext_vector_type(8))) short short8;
typedef __attribute__((ext_vector_type(4))) float f32x4;
typedef unsigned long long u64;
typedef unsigned int u32;
typedef unsigned short u16;

// ---------- helpers ----------

__device__ __forceinline__ u16 bf_rne(float f) {
    // round-to-nearest-even fp32 -> bf16 (inputs are finite)
    u32 u = __float_as_uint(f);
    u32 r = (u + 0x7FFFu + ((u >> 16) & 1u)) >> 16;
    return (u16)r;
}

__device__ __forceinline__ u32 fkey32(float f) {
    // monotonic (order-preserving) float -> uint transform
    u32 u = __float_as_uint(f);
    return u ^ ((u32)((int)u >> 31) | 0x80000000u);
}

__device__ __forceinline__ void ins2(u32 &k1, u32 &k2, u32 c) {
    // insert candidate into sorted (k1<=k2); strict < keeps earlier (smaller id) on ties
    bool lt1 = c < k1;
    u32 nk2 = lt1 ? k1 : (c < k2 ? c : k2);
    k1 = lt1 ? c : k1;
    k2 = nk2;
}

__device__ __forceinline__ void cswap32(u32 &a, u32 &b) {
    u32 lo = a < b ? a : b;
    u32 hi = a < b ? b : a;
    a = lo; b = hi;
}

__device__ __forceinline__ void gll16(const void* g, void* l) {
    // async global->LDS, 16B per lane; LDS dest = wave-uniform base + lane*16
    __builtin_amdgcn_global_load_lds((const __attribute__((address_space(1))) void*)g,
                                     (__attribute__((address_space(3))) void*)l,
                                     16, 0, 0);
}

// ---------- prep: fp32 -> bf16 (RNE) + optional row sum-of-squares ----------

__global__ __launch_bounds__(256) void prep_bf16(const float* __restrict__ src,
                                                 u16* __restrict__ hp,
                                                 float* __restrict__ np) {
    int row  = blockIdx.x * 4 + (threadIdx.x >> 6);
    int lane = threadIdx.x & 63;
    const float* s = src + (size_t)row * D_DIM + lane * 8;
    float4 a = *(const float4*)(s);
    float4 b = *(const float4*)(s + 4);
    float v[8] = {a.x, a.y, a.z, a.w, b.x, b.y, b.z, b.w};
    short8 hv;
    float sum = 0.f;
#pragma unroll
    for (int j = 0; j < 8; j++) {
        hv[j] = (short)bf_rne(v[j]);
        sum += v[j] * v[j];
    }
    *(short8*)(hp + (size_t)row * D_DIM + lane * 8) = hv;
    if (np != nullptr) {
#pragma unroll
        for (int mask = 1; mask < 64; mask <<= 1)
            sum += __shfl_xor(sum, mask, 64);
        if (lane == 0) np[row] = sum;
    }
}

// ---------- main: bf16 GEMM (approx -2*x.c) + per-tile top-2, 8-code-tile sweep ----------
// Block = 128 rows x 8 code-tiles (its XCD's share). Continuous 64-K-step 2-phase
// pipeline (prefetch crosses tile boundaries, never drains until block end).
// Per tile: per-lane top-2 (u32 key = 19 order bits | 13-bit id) -> LDS -> 128-thread
// scan -> per-tile top-2. finalize merges to global top-4 + exact fp32 re-rank.

__global__ __launch_bounds__(256, 2) void qgemm(const u16* __restrict__ xh,
                                                const u16* __restrict__ ch,
                                                const float* __restrict__ cnorm,
                                                uint2* __restrict__ tileres) {
    // LDS: 2 bufs x (A [128][64] 16KB + B [128][64] 16KB) = 64KB.
    // Epilogue scratch (32KB) overlays buf1: every tile's last K-step computes
    // FROM buf1 (step parity: s=8j+7 is odd) and prefetches INTO buf0, so buf1
    // is provably idle between the end-of-tile barrier and the next prefetch.
    __shared__ char smem[65536];

    int bid   = blockIdx.x;
    int xcd   = bid & 7;       // this XCD owns tileN = xcd*8 .. xcd*8+7 (1MB ch, L2-resident)
    int tileM = bid >> 3;      // 0..255

    int tid  = threadIdx.x;
    int lane = tid & 63;
    int w    = tid >> 6;
    int wr   = w >> 1, wc = w & 1;   // wave -> 64x64 output quadrant

    // Staging geometry: q = tid + 256*i; row=q>>3; chunk=q&7. LDS written LINEARLY
    // (global_load_lds constraint); XOR swizzle chunk^=(row&7) applied on the GLOBAL
    // source (rule #21). ds_read side xors the same -> 2 lanes/bank-quad = free.
    size_t aoff[4], boff0[4];
    int ldsq[4];
#pragma unroll
    for (int i = 0; i < 4; i++) {
        int q   = tid + 256 * i;
        int row = q >> 3;
        int csw = (q & 7) ^ (row & 7);
        aoff[i]  = ((size_t)(tileM * BM + row)) * D_DIM + csw * 8;
        boff0[i] = ((size_t)row) * D_DIM + csw * 8;
        ldsq[i]  = (w * 64 + 256 * i) * 16;   // wave-uniform LDS byte base
    }
    const size_t btile = (size_t)BN * D_DIM;   // 65536 elements per code-tile

    // prologue: stage (j=0, kk=0) into buf0
#pragma unroll
    for (int i = 0; i < 4; i++) {
        gll16(xh + aoff[i], smem + 0 + ldsq[i]);
        gll16(ch + (size_t)(xcd * TPB) * btile + boff0[i], smem + 16384 + ldsq[i]);
    }
    __syncthreads();

#pragma unroll 1
    for (int j = 0; j < TPB; j++) {
        f32x4 acc[4][4];
#pragma unroll
        for (int m = 0; m < 4; m++)
#pragma unroll
            for (int n = 0; n < 4; n++)
                acc[m][n] = (f32x4){0.f, 0.f, 0.f, 0.f};

#pragma unroll
        for (int t = 0; t < 8; t++) {
            int s   = j * 8 + t;
            int cur = s & 1, nxt = cur ^ 1;
            // prefetch next K-step (possibly next tile's step 0) FIRST
            if (t != 7) {
                int kk2 = (t + 1) * BK;
#pragma unroll
                for (int i = 0; i < 4; i++) {
                    gll16(xh + aoff[i] + kk2, smem + nxt * 32768 + ldsq[i]);
                    gll16(ch + (size_t)(xcd * TPB + j) * btile + boff0[i] + kk2,
                          smem + nxt * 32768 + 16384 + ldsq[i]);
                }
            } else if (j < TPB - 1) {
#pragma unroll
                for (int i = 0; i < 4; i++) {
                    gll16(xh + aoff[i], smem + nxt * 32768 + ldsq[i]);
                    gll16(ch + (size_t)(xcd * TPB + j + 1) * btile + boff0[i],
                          smem + nxt * 32768 + 16384 + ldsq[i]);
                }
            }
            const char* base = smem + cur * 32768;

            int klo = (lane >> 4) * 16;
            short8 b[2][4];
#pragma unroll
            for (int tt = 0; tt < 2; tt++)
#pragma unroll
                for (int n = 0; n < 4; n++) {
                    int rb = wc * 64 + n * 16 + (lane & 15);
                    int cbyte = tt * 64 + klo;
                    int ad = rb * 128 + (cbyte ^ ((rb & 7) << 4));
                    b[tt][n] = *(const short8*)(base + 16384 + ad);
                }
#pragma unroll
            for (int m = 0; m < 4; m++) {
                int ra = wr * 64 + m * 16 + (lane & 15);
#pragma unroll
                for (int tt = 0; tt < 2; tt++) {
                    int cbyte = tt * 64 + klo;
                    int ad = ra * 128 + (cbyte ^ ((ra & 7) << 4));
                    short8 a = *(const short8*)(base + ad);
#pragma unroll
                    for (int n = 0; n < 4; n++)
                        acc[m][n] = __builtin_amdgcn_mfma_f32_16x16x32_bf16(a, b[tt][n], acc[m][n], 0, 0, 0);
                }
            }
            __syncthreads();   // drains prefetch vmcnt + all waves done with buf[cur]
        }

        // ---- per-tile epilogue (butterfly-free) ----
        int tileN = xcd * TPB + j;
        int cq = lane >> 4, cc = lane & 15;
        float cn[4];
#pragma unroll
        for (int n = 0; n < 4; n++)
            cn[n] = cnorm[tileN * BN + wc * 64 + n * 16 + cc];

        char* sc = smem + 32768;   // 32KB scratch = buf1 (idle here; see header comment)
        u32 idb = (u32)(tileN * BN + wc * 64 + cc);

#pragma unroll
        for (int m = 0; m < 4; m++) {
#pragma unroll
            for (int r = 0; r < 4; r++) {
                u32 k1 = 0xFFFFFFFFu, k2 = 0xFFFFFFFFu;
#pragma unroll
                for (int n = 0; n < 4; n++) {
                    float d = fmaf(-2.f, acc[m][n][r], cn[n]);   // == cnorm - 2*x.c exactly
                    u32 key = (fkey32(d) & 0xFFFFE000u) | (idb + n * 16);
                    ins2(k1, k2, key);
                }
                int row = wr * 64 + m * 16 + cq * 4 + r;   // C/D: row=(lane>>4)*4+reg
                int off = wc * 16384 + row * 128 + ((cc * 8) ^ ((row & 7) << 4));
                *(u64*)(sc + off) = ((u64)k2 << 32) | k1;
            }
        }
        __syncthreads();
        if (tid < 128) {
            int row = tid;
            u32 r1 = 0xFFFFFFFFu, r2 = 0xFFFFFFFFu;
#pragma unroll
            for (int h = 0; h < 2; h++)
#pragma unroll
                for (int i = 0; i < 8; i++) {
                    int off = h * 16384 + row * 128 + ((i * 16) ^ ((row & 7) << 4));
                    uint4 e = *(const uint4*)(sc + off);   // {k1,k2} x 2 lanes, id-ascending
                    ins2(r1, r2, e.x); ins2(r1, r2, e.y);
                    ins2(r1, r2, e.z); ins2(r1, r2, e.w);
                }
            tileres[(size_t)(tileM * BM + row) * NTILES + tileN] = (uint2){r1, r2};
        }
        __syncthreads();   // scratch/buf1 free before next tile's first prefetch
    }
}

// ---------- finalize: global top-4 merge (u32 keys), exact fp32 re-rank of 4,
//            gather emb (STE form), ids (as float), loss = 1.25 * ||x - emb||^2 ----------

__global__ __launch_bounds__(256) void finalize(const float* __restrict__ x, const float* __restrict__ cb,
                                                const uint2* __restrict__ tileres,
                                                float* __restrict__ emb, float* __restrict__ idsf,
                                                float* __restrict__ lossf) {
    int row  = blockIdx.x * 4 + (threadIdx.x >> 6);
    int lane = threadIdx.x & 63;

    uint2 t = tileres[(size_t)row * NTILES + lane];   // 64 tiles == 64 lanes
    u32 k0 = t.x, k1 = t.y, k2 = 0xFFFFFFFFu, k3 = 0xFFFFFFFFu;
    // butterfly: lowest-4 of two sorted 4-lists via bitonic half-cleaner
#pragma unroll
    for (int mask = 1; mask < 64; mask <<= 1) {
        u32 p0 = (u32)__shfl_xor((int)k0, mask, 64);
        u32 p1 = (u32)__shfl_xor((int)k1, mask, 64);
        u32 p2 = (u32)__shfl_xor((int)k2, mask, 64);
        u32 p3 = (u32)__shfl_xor((int)k3, mask, 64);
        u32 m0 = k0 < p3 ? k0 : p3;
        u32 m1 = k1 < p2 ? k1 : p2;
        u32 m2 = k2 < p1 ? k2 : p1;
        u32 m3 = k3 < p0 ? k3 : p0;
        cswap32(m0, m2); cswap32(m1, m3); cswap32(m0, m1); cswap32(m2, m3);
        k0 = m0; k1 = m1; k2 = m2; k3 = m3;
    }
    u32 id0 = k0 & 8191u, id1 = k1 & 8191u, id2 = k2 & 8191u, id3 = k3 & 8191u;

    const float* xr = x + (size_t)row * D_DIM + lane * 8;
    float4 xa = *(const float4*)xr, xb = *(const float4*)(xr + 4);
    float xv[8] = {xa.x, xa.y, xa.z, xa.w, xb.x, xb.y, xb.z, xb.w};

    const float* c0p = cb + (size_t)id0 * D_DIM + lane * 8;
    const float* c1p = cb + (size_t)id1 * D_DIM + lane * 8;
    const float* c2p = cb + (size_t)id2 * D_DIM + lane * 8;
    const float* c3p = cb + (size_t)id3 * D_DIM + lane * 8;
    float4 a0 = *(const float4*)c0p, b0 = *(const float4*)(c0p + 4);
    float4 a1 = *(const float4*)c1p, b1 = *(const float4*)(c1p + 4);
    float4 a2 = *(const float4*)c2p, b2 = *(const float4*)(c2p + 4);
    float4 a3 = *(const float4*)c3p, b3 = *(const float4*)(c3p + 4);
    float v0[8] = {a0.x, a0.y, a0.z, a0.w, b0.x, b0.y, b0.z, b0.w};
    float v1[8] = {a1.x, a1.y, a1.z, a1.w, b1.x, b1.y, b1.z, b1.w};
    float v2[8] = {a2.x, a2.y, a2.z, a2.w, b2.x, b2.y, b2.z, b2.w};
    float v3[8] = {a3.x, a3.y, a3.z, a3.w, b3.x, b3.y, b3.z, b3.w};

    float s0 = 0.f, s1 = 0.f, s2 = 0.f, s3 = 0.f;
#pragma unroll
    for (int jj = 0; jj < 8; jj++) {
        float d0 = xv[jj] - v0[jj]; s0 += d0 * d0;
        float d1 = xv[jj] - v1[jj]; s1 += d1 * d1;
        float d2 = xv[jj] - v2[jj]; s2 += d2 * d2;
        float d3 = xv[jj] - v3[jj]; s3 += d3 * d3;
    }
#pragma unroll
    for (int mask = 1; mask < 64; mask <<= 1) {
        s0 += __shfl_xor(s0, mask, 64);
        s1 += __shfl_xor(s1, mask, 64);
        s2 += __shfl_xor(s2, mask, 64);
        s3 += __shfl_xor(s3, mask, 64);
    }

    // exact argmin over the 4 candidates; tie -> smaller index (jnp.argmin first-occurrence)
    float bs = s0; u32 bi = id0; int bj = 0;
    bool t1 = (s1 < bs) || (s1 == bs && id1 < bi); bs = t1 ? s1 : bs; bi = t1 ? id1 : bi; bj = t1 ? 1 : bj;
    bool t2 = (s2 < bs) || (s2 == bs && id2 < bi); bs = t2 ? s2 : bs; bi = t2 ? id2 : bi; bj = t2 ? 2 : bj;
    bool t3 = (s3 < bs) || (s3 == bs && id3 < bi); bs = t3 ? s3 : bs; bi = t3 ? id3 : bi; bj = t3 ? 3 : bj;

    float ev[8];
#pragma unroll
    for (int jj = 0; jj < 8; jj++) {
        float cj = (bj == 0) ? v0[jj] : (bj == 1) ? v1[jj] : (bj == 2) ? v2[jj] : v3[jj];
        ev[jj] = xv[jj] + (cj - xv[jj]);   // replicate reference's x + (emb - x)
    }
    float* op = emb + (size_t)row * D_DIM + lane * 8;
    *(float4*)op       = (float4){ev[0], ev[1], ev[2], ev[3]};
    *(float4*)(op + 4) = (float4){ev[4], ev[5], ev[6], ev[7]};

    if (lane == 0) {
        idsf[row]  = (float)bi;
        lossf[row] = 1.25f * bs;   // emb_loss + 0.25*query_loss, both == ||x-emb||^2
    }
}

// ---------- launch ----------

extern "C" void kernel_launch(void* const* d_in, const int* in_sizes, int n_in,
                              void* d_out, int out_size, void* d_ws, size_t ws_size,
                              hipStream_t stream) {
    const float* x  = (const float*)d_in[0];
    const float* cb = (const float*)d_in[1];
    char* ws = (char*)d_ws;

    // workspace layout (bytes)
    u16*   xh    = (u16*)(ws + 0);               // 32 MB
    u16*   ch    = (u16*)(ws + 33554432);        //  8 MB
    float* cnorm = (float*)(ws + 41943040);      // 32 KB
    uint2* tileres = (uint2*)(ws + 41975808);    // 16 MB (total ~58 MB)

    float* emb   = (float*)d_out;
    float* idsf  = emb + (size_t)N_ROWS * D_DIM;
    float* lossf = idsf + N_ROWS;

    prep_bf16<<<dim3(K_CODES / 4), dim3(256), 0, stream>>>(cb, ch, cnorm);
    prep_bf16<<<dim3(N_ROWS / 4),  dim3(256), 0, stream>>>(x, xh, nullptr);
    qgemm<<<dim3((N_ROWS / BM) * 8), dim3(256), 0, stream>>>(xh, ch, cnorm, tileres);
    finalize<<<dim3(N_ROWS / 4), dim3(256), 0, stream>>>(x, cb, tileres, emb, idsf, lossf);
}